// Round 2
// baseline (272.427 us; speedup 1.0000x reference)
//
#include <hip/hip_runtime.h>
#include <math.h>

#define D  32
#define BN 16384
#define PP 16

typedef __bf16 bf16x8 __attribute__((ext_vector_type(8)));
typedef __bf16 bf16x4 __attribute__((ext_vector_type(4)));
typedef float  floatx4 __attribute__((ext_vector_type(4)));

#define K1 1.44269504088896341f      // log2(e)
#define K2 2.88539008177792681f      // 2*log2(e)

// LDS image: only the MFMA A-operands.
//   Wu  = Wih[:,0:32] bf16 [gate][stride 40]  (80 B rows)
//   Whh = bf16 [gate][stride 40]
// acc-init comes from GLOBAL combined tables (f32, L2-resident), software-
// pipelined one step ahead so the L2 gather latency hides under compute:
//   T0[hop][k][g]    = bias[g] + Wih[g][32:64]@ent[k]          (step 0)
//   T [hop][j][k][g] = bias[g] + Wih[g][0:32]@rel[j]
//                              + Wih[g][32:64]@ent[k]          (steps >=1)
#define WU_OFF     0
#define WHH_OFF    10240
#define WIMG_BYTES 20480
#define H_OFF      20480
#define LDS_BYTES  (WIMG_BYTES + 4 * 1280)   // + H: 4 waves x 1 chain x 16 x 80B

__device__ __forceinline__ float sigf(float x) {
    float e = __builtin_amdgcn_exp2f(-x * K1);
    return __builtin_amdgcn_rcpf(1.0f + e);
}
__device__ __forceinline__ float logsigf(float x) {
    float ax = fabsf(x);
    float l = log1pf(__expf(-ax));
    return (x >= 0.0f) ? -l : x - l;
}
__device__ __forceinline__ bf16x8 loadu8(const float* __restrict__ p) {
    float4 a = ((const float4*)p)[0], b = ((const float4*)p)[1];
    bf16x8 r = { (__bf16)a.x, (__bf16)a.y, (__bf16)a.z, (__bf16)a.w,
                 (__bf16)b.x, (__bf16)b.y, (__bf16)b.z, (__bf16)b.w };
    return r;
}

// ---------------------------------------------------------------------------
// ids 0..16383           : weight images (bf16, Wu/Whh per hop)
// ids 16384..278527      : T  (2 hops x 32 j x 32 k x 128 g, f32)
// ids 278528..286719     : T0 (2 hops x 32 k x 128 g, f32)
__global__ __launch_bounds__(256)
void prep_tables(const float* __restrict__ ent, const float* __restrict__ rel,
                 const float* __restrict__ wih0, const float* __restrict__ whh0,
                 const float* __restrict__ bih0, const float* __restrict__ bhh0,
                 const float* __restrict__ wih1, const float* __restrict__ whh1,
                 const float* __restrict__ bih1, const float* __restrict__ bhh1,
                 float* __restrict__ T0, float* __restrict__ T,
                 float* __restrict__ wimg)
{
    const int id = blockIdx.x * 256 + threadIdx.x;
    if (id < 16384) {                            // weight images
        const int hop  = id >> 13;
        const int rest = id & 8191;
        const int mat  = rest >> 12;             // 0 = Wu, 1 = Whh
        const int e    = rest & 4095;
        const int gate = e >> 5, d = e & 31;
        float v = mat ? (hop ? whh1 : whh0)[(size_t)gate * 32 + d]
                      : (hop ? wih1 : wih0)[(size_t)gate * 64 + d];
        __bf16* base = (__bf16*)((char*)wimg + hop * WIMG_BYTES + mat * 10240);
        base[gate * 40 + d] = (__bf16)v;
    } else if (id < 16384 + 262144) {            // combined table T
        const int idt = id - 16384;
        const int hop = idt >> 17;
        const int r   = idt & 131071;            // j*4096 + k*128 + g
        const int j   = r >> 12;
        const int k   = (r >> 7) & 31;
        const int g   = r & 127;
        const float* wih = hop ? wih1 : wih0;
        const float4* w4 = (const float4*)(wih + (size_t)g * 64);
        const float4* r4 = (const float4*)(rel + (size_t)j * 32);
        const float4* e4 = (const float4*)(ent + (size_t)k * 32);
        float a = hop ? bih1[g] + bhh1[g] : bih0[g] + bhh0[g];
        #pragma unroll
        for (int i = 0; i < 8; ++i) {
            float4 w = w4[i], x = r4[i];
            a = fmaf(w.x, x.x, a); a = fmaf(w.y, x.y, a);
            a = fmaf(w.z, x.z, a); a = fmaf(w.w, x.w, a);
        }
        #pragma unroll
        for (int i = 0; i < 8; ++i) {
            float4 w = w4[8 + i], x = e4[i];
            a = fmaf(w.x, x.x, a); a = fmaf(w.y, x.y, a);
            a = fmaf(w.z, x.z, a); a = fmaf(w.w, x.w, a);
        }
        T[(size_t)hop * 131072 + r] = a;
    } else if (id < 16384 + 262144 + 8192) {     // step-0 table T0
        const int idb = id - 16384 - 262144;
        const int hop = idb >> 12;
        const int k   = (idb >> 7) & 31;
        const int g   = idb & 127;
        const float* wih = hop ? wih1 : wih0;
        const float4* w4 = (const float4*)(wih + (size_t)g * 64);
        const float4* e4 = (const float4*)(ent + (size_t)k * 32);
        float a = hop ? bih1[g] + bhh1[g] : bih0[g] + bhh0[g];
        #pragma unroll
        for (int i = 0; i < 8; ++i) {
            float4 w = w4[8 + i], x = e4[i];
            a = fmaf(w.x, x.x, a); a = fmaf(w.y, x.y, a);
            a = fmaf(w.z, x.z, a); a = fmaf(w.w, x.w, a);
        }
        T0[(size_t)hop * 4096 + k * 128 + g] = a;
    }
}

// nonlin in C-layout D[gate][pair] (verified R10): lane (q=lane>>4, p=lane&15),
// tile mt holds gates 16mt+4q+r of pair p -> unit quartets hf=0: 4q+r,
// hf=1: 16+4q+r. 4 exp2 + 2 rcp + 1 exp2 per unit.
template<bool FIRST, bool LAST>
__device__ __forceinline__ void nonlin(
    floatx4* __restrict__ acc, float* __restrict__ cst,
    float* __restrict__ hlo, float* __restrict__ hhi,
    char* __restrict__ Hw, int q, int bnl)
{
    #pragma unroll
    for (int hf = 0; hf < 2; ++hf) {
        float* hout = hf ? hhi : hlo;
        #pragma unroll
        for (int r = 0; r < 4; ++r) {
            float gi = acc[0 + hf][r], gf = acc[2 + hf][r],
                  gg = acc[4 + hf][r], go = acc[6 + hf][r];
            float Ai = 1.0f + __builtin_amdgcn_exp2f(-gi * K1);
            float Af = 1.0f + __builtin_amdgcn_exp2f(-gf * K1);
            float G2 = __builtin_amdgcn_exp2f(gg * K2);
            float Gp = G2 + 1.0f, Gm = G2 - 1.0f;
            float cold = FIRST ? 0.0f : cst[hf * 4 + r];
            float num = cold * Ai * Gp + Gm * Af;
            float c = num * __builtin_amdgcn_rcpf(Af * Ai * Gp);
            cst[hf * 4 + r] = c;
            float Ao = 1.0f + __builtin_amdgcn_exp2f(-go * K1);
            float C2 = __builtin_amdgcn_exp2f(c * K2);
            hout[r] = (C2 - 1.0f) * __builtin_amdgcn_rcpf(Ao * (C2 + 1.0f));
        }
    }
    if (!LAST) {
        bf16x4 plo = { (__bf16)hlo[0], (__bf16)hlo[1], (__bf16)hlo[2], (__bf16)hlo[3] };
        bf16x4 phi = { (__bf16)hhi[0], (__bf16)hhi[1], (__bf16)hhi[2], (__bf16)hhi[3] };
        *(bf16x4*)(Hw + bnl * 80 + 8 * q)      = plo;
        *(bf16x4*)(Hw + bnl * 80 + 32 + 8 * q) = phi;
    }
}

// Grid 8192: hop = bid&1, idx = bid>>1. 4 waves x 1 chain (batch idx*4+w).
// Software pipeline: acc0+acc1 T-gathers issued at block start (latency hides
// under index/image/barrier preamble); acc2 issued after step-0 nonlin
// (hides under step-1 compute). Peak unified regs ~105 -> 4 waves/SIMD.
__global__ __launch_bounds__(256, 4)
void hop_mfma(const float* __restrict__ user_table,
              const int*   __restrict__ users,
              const int*   __restrict__ items,
              const int*   __restrict__ lp0,     // (NE,P,3)
              const int*   __restrict__ lp1,     // (NE,P,5)
              const float* __restrict__ wimg,
              const float* __restrict__ T0g,
              const float* __restrict__ Tg,
              float* __restrict__ F0,            // (B,32) sum_p h
              float* __restrict__ F1)
{
    __shared__ __align__(16) char lds[LDS_BYTES];

    const bool second = blockIdx.x & 1;
    const int  idx    = blockIdx.x >> 1;
    const int tid  = threadIdx.x;
    const int lane = tid & 63;
    const int wave = tid >> 6;
    const int q    = lane >> 4;
    const int bnl  = lane & 15;

    // ---- indices first: T gathers must issue as early as possible ----------
    const int fb = idx * 4 + wave;
    const int L  = second ? 5 : 3;
    const int* lp = second ? lp1 : lp0;
    const int* __restrict__ il = lp + ((size_t)items[fb] * PP + bnl) * L;
    int sq[5];
    #pragma unroll
    for (int i = 0; i < 5; ++i) sq[i] = (i < L) ? il[i] : 0;

    const float* T0h = T0g + (second ? 4096 : 0);
    const float* Th  = Tg  + (second ? 131072 : 0);
    const float* t0p = T0h + sq[0] * 128 + 4 * q;
    const float* t1p = Th + (((sq[1]) << 5) + sq[2]) * 128 + 4 * q;

    floatx4 acc0[8], acc1[8];
    #pragma unroll
    for (int mt = 0; mt < 8; ++mt) acc0[mt] = *(const floatx4*)(t0p + 16 * mt);
    #pragma unroll
    for (int mt = 0; mt < 8; ++mt) acc1[mt] = *(const floatx4*)(t1p + 16 * mt);

    bf16x8 bu = loadu8(user_table + (size_t)users[fb] * D + q * 8);

    // ---- weight image -> LDS (20480 B = 1280 float4, 5 per thread) ---------
    {
        const float4* g4 = (const float4*)((const char*)wimg +
                                           (second ? WIMG_BYTES : 0));
        float4* l4 = (float4*)lds;
        #pragma unroll
        for (int i = 0; i < 5; ++i) l4[i * 256 + tid] = g4[i * 256 + tid];
    }
    const char* Wu  = lds + WU_OFF;
    const char* Whh = lds + WHH_OFF;
    char* Hw = lds + H_OFF + wave * 1280;

    __syncthreads();   // image ready

    float cst[8], hlo[4], hhi[4];

    // ---- step 0: acc0 = T0[seed] ; += Wu @ u -------------------------------
    #pragma unroll
    for (int mt = 0; mt < 8; ++mt) {
        bf16x8 wu = *(const bf16x8*)(Wu + (16 * mt + bnl) * 80 + q * 16);
        acc0[mt] = __builtin_amdgcn_mfma_f32_16x16x32_bf16(wu, bu, acc0[mt], 0, 0, 0);
    }
    nonlin<true, false>(acc0, cst, hlo, hhi, Hw, q, bnl);

    // prefetch step-2 tiles (hop 1 only) now that acc0 is dead
    floatx4 acc2[8];
    if (second) {
        const float* t2p = Th + (((sq[3]) << 5) + sq[4]) * 128 + 4 * q;
        #pragma unroll
        for (int mt = 0; mt < 8; ++mt) acc2[mt] = *(const floatx4*)(t2p + 16 * mt);
    }

    // ---- step 1: acc1 = T[j][k] ; += Whh @ h -------------------------------
    {
        bf16x8 bh = *(const bf16x8*)(Hw + bnl * 80 + q * 16);
        #pragma unroll
        for (int mt = 0; mt < 8; ++mt) {
            bf16x8 wh = *(const bf16x8*)(Whh + (16 * mt + bnl) * 80 + q * 16);
            acc1[mt] = __builtin_amdgcn_mfma_f32_16x16x32_bf16(wh, bh, acc1[mt], 0, 0, 0);
        }
        if (second) nonlin<false, false>(acc1, cst, hlo, hhi, Hw, q, bnl);
        else        nonlin<false, true >(acc1, cst, hlo, hhi, Hw, q, bnl);
    }

    // ---- step 2 (hop 1 only) -----------------------------------------------
    if (second) {
        bf16x8 bh = *(const bf16x8*)(Hw + bnl * 80 + q * 16);
        #pragma unroll
        for (int mt = 0; mt < 8; ++mt) {
            bf16x8 wh = *(const bf16x8*)(Whh + (16 * mt + bnl) * 80 + q * 16);
            acc2[mt] = __builtin_amdgcn_mfma_f32_16x16x32_bf16(wh, bh, acc2[mt], 0, 0, 0);
        }
        nonlin<false, true>(acc2, cst, hlo, hhi, Hw, q, bnl);
    }

    // ---- sum over pairs (reduce across bnl lanes), write F -----------------
    #pragma unroll
    for (int r = 0; r < 4; ++r) {
        #pragma unroll
        for (int m = 1; m < 16; m <<= 1) {
            hlo[r] += __shfl_xor(hlo[r], m);
            hhi[r] += __shfl_xor(hhi[r], m);
        }
    }
    if (bnl == 0) {
        float* Fout = (second ? F1 : F0);
        float4 vlo = { hlo[0], hlo[1], hlo[2], hlo[3] };
        float4 vhi = { hhi[0], hhi[1], hhi[2], hhi[3] };
        *(float4*)(Fout + (size_t)fb * D + 4 * q)      = vlo;
        *(float4*)(Fout + (size_t)fb * D + 16 + 4 * q) = vhi;
    }
}

// Per b: emb0=(ent[items]+F0)@W^T+b ; emb1=(emb0+F1)@W^T+b ; score=dot(u,emb1)
__global__ __launch_bounds__(256)
void chain_score(const float* __restrict__ user_table,
                 const float* __restrict__ ent_table,
                 const float* __restrict__ agg_w,
                 const float* __restrict__ agg_b,
                 const int*   __restrict__ users,
                 const int*   __restrict__ items,
                 const int*   __restrict__ ratings,
                 const float* __restrict__ F0,
                 const float* __restrict__ F1,
                 float* __restrict__ out,
                 float* __restrict__ partials)
{
    __shared__ float s[8][33];
    __shared__ float red[8];
    const int tid = threadIdx.x;
    const int bb  = tid >> 5;
    const int j   = tid & 31;
    const int b   = blockIdx.x * 8 + bb;
    const int it  = items[b];

    s[bb][j] = ent_table[(size_t)it * D + j] + F0[(size_t)b * D + j];
    __syncthreads();
    const float* __restrict__ w = agg_w + (size_t)j * D;
    float e0 = agg_b[j];
    #pragma unroll
    for (int k = 0; k < D; ++k) e0 = fmaf(s[bb][k], w[k], e0);
    __syncthreads();
    s[bb][j] = e0 + F1[(size_t)b * D + j];
    __syncthreads();
    float e1 = agg_b[j];
    #pragma unroll
    for (int k = 0; k < D; ++k) e1 = fmaf(s[bb][k], w[k], e1);

    float prod = user_table[(size_t)users[b] * D + j] * e1;
    #pragma unroll
    for (int m = 1; m < 32; m <<= 1) prod += __shfl_xor(prod, m);
    if (j == 0) {
        out[1 + b]      = sigf(prod);
        out[1 + BN + b] = (float)it;
        float r = (float)ratings[b];
        red[bb] = r * logsigf(prod) + (1.0f - r) * logsigf(-prod);
    }
    __syncthreads();
    if (tid == 0) {
        float t = 0.0f;
        #pragma unroll
        for (int qq = 0; qq < 8; ++qq) t += red[qq];
        partials[blockIdx.x] = t;
    }
}

__global__ __launch_bounds__(256)
void loss_kernel(const float* __restrict__ partials, float* __restrict__ out)
{
    __shared__ float red[4];
    const int t = threadIdx.x;
    float v = 0.0f;
    #pragma unroll
    for (int qq = 0; qq < 8; ++qq) v += partials[qq * 256 + t];
    #pragma unroll
    for (int m = 1; m < 64; m <<= 1) v += __shfl_xor(v, m);
    if ((t & 63) == 0) red[t >> 6] = v;
    __syncthreads();
    if (t == 0) out[0] = -(red[0] + red[1] + red[2] + red[3]) / (float)BN;
}

extern "C" void kernel_launch(void* const* d_in, const int* in_sizes, int n_in,
                              void* d_out, int out_size, void* d_ws, size_t ws_size,
                              hipStream_t stream)
{
    const float* user_table = (const float*)d_in[0];
    const float* ent_table  = (const float*)d_in[1];
    const float* rel_table  = (const float*)d_in[2];
    const float* w_ih0 = (const float*)d_in[3];
    const float* w_hh0 = (const float*)d_in[4];
    const float* b_ih0 = (const float*)d_in[5];
    const float* b_hh0 = (const float*)d_in[6];
    const float* w_ih1 = (const float*)d_in[7];
    const float* w_hh1 = (const float*)d_in[8];
    const float* b_ih1 = (const float*)d_in[9];
    const float* b_hh1 = (const float*)d_in[10];
    const float* agg_w = (const float*)d_in[11];
    const float* agg_b = (const float*)d_in[12];
    const int* users   = (const int*)d_in[13];
    const int* items   = (const int*)d_in[14];
    const int* ratings = (const int*)d_in[15];
    const int* lp0     = (const int*)d_in[16];
    const int* lp1     = (const int*)d_in[17];
    float* out = (float*)d_out;

    float* ws       = (float*)d_ws;
    float* F0       = ws;                              // BN*32
    float* F1       = F0 + (size_t)BN * D;             // BN*32
    float* partials = F1 + (size_t)BN * D;             // 2048
    float* T0       = partials + 2048;                 // 2*32*128   = 8192
    float* T        = T0 + 8192;                       // 2*1024*128 = 262144
    float* wimg     = T + 262144;                      // 2*WIMG_BYTES bytes

    prep_tables<<<1120, 256, 0, stream>>>(ent_table, rel_table,
        w_ih0, w_hh0, b_ih0, b_hh0, w_ih1, w_hh1, b_ih1, b_hh1, T0, T, wimg);
    hop_mfma<<<8192, 256, 0, stream>>>(
        user_table, users, items, lp0, lp1, wimg, T0, T, F0, F1);
    chain_score<<<BN / 8, 256, 0, stream>>>(
        user_table, ent_table, agg_w, agg_b, users, items, ratings,
        F0, F1, out, partials);
    loss_kernel<<<1, 256, 0, stream>>>(partials, out);
}